// Round 7
// baseline (2512.832 us; speedup 1.0000x reference)
//
#include <hip/hip_runtime.h>
#include <hip/hip_fp16.h>
#include <math.h>

#define C 40
#define NQ 10   // valid uint2 (4-half groups) per row
#define NBIN 256

// ---------------- mask dtype detection ----------------
__global__ void k_detect(const unsigned int* __restrict__ w, int nwords,
                         unsigned int* __restrict__ flags) {
    int i = blockIdx.x * blockDim.x + threadIdx.x;
    unsigned int viol = 0;
    for (; i < nwords; i += gridDim.x * blockDim.x) {
        unsigned int v = w[i];
        if (!(v == 0u || v == 1u)) viol |= 1u;
        if (!(v == 0u || v == 0x3F800000u)) viol |= 2u;
    }
    if (viol) atomicOr(flags, viol);
}

__device__ __forceinline__ bool read_mask(const void* mp, unsigned int fl, int n) {
    if ((fl & 1u) == 0u) return ((const int*)mp)[n] != 0;        // int32 {0,1}
    if ((fl & 2u) == 0u) return ((const float*)mp)[n] != 0.0f;   // float {0,1}
    return ((const unsigned char*)mp)[n] != 0;                   // bool bytes
}

// ---------------- degree / norm ----------------
__global__ void k_deg(const int* __restrict__ dst, int* __restrict__ deg, int E) {
    int i = blockIdx.x * blockDim.x + threadIdx.x;
    if (i < E) atomicAdd(&deg[dst[i]], 1);
}

__global__ void k_dinv(const int* __restrict__ deg, float* __restrict__ dinv, int n) {
    int i = blockIdx.x * blockDim.x + threadIdx.x;
    if (i < n) {
        int d = deg[i];
        dinv[i] = (d > 0) ? rsqrtf((float)d) : 0.0f;
    }
}

// ---------------- counting sort by degree: hist -> scan -> scatter ----------
__global__ void k_hist(const int* __restrict__ deg, int* __restrict__ hist, int n) {
    int i = blockIdx.x * blockDim.x + threadIdx.x;
    if (i < n) atomicAdd(&hist[min(deg[i], NBIN - 1)], 1);
}

__global__ void k_binscan(const int* __restrict__ hist, int* __restrict__ binptr) {
    __shared__ int sm[NBIN];
    int tid = threadIdx.x;
    int v = hist[tid];
    sm[tid] = v;
    __syncthreads();
    for (int o = 1; o < NBIN; o <<= 1) {
        int t = (tid >= o) ? sm[tid - o] : 0;
        __syncthreads();
        sm[tid] += t;
        __syncthreads();
    }
    binptr[tid] = sm[tid] - v;  // exclusive
}

__global__ void k_sort(const int* __restrict__ deg, const int* __restrict__ binptr,
                       int* __restrict__ binfill, int* __restrict__ perm,
                       int* __restrict__ pos, int n) {
    int i = blockIdx.x * blockDim.x + threadIdx.x;
    if (i < n) {
        int b = min(deg[i], NBIN - 1);
        int r = atomicAdd(&binfill[b], 1);
        int p = binptr[b] + r;
        perm[p] = i;
        pos[i] = p;
    }
}

// ---------------- quad max-degree over SORTED nodes ----------------
__global__ void k_qlen(const int* __restrict__ deg, const int* __restrict__ perm,
                       int* __restrict__ qlen, int T, int n) {
    int t = blockIdx.x * blockDim.x + threadIdx.x;
    if (t < T) {
        int m = 0;
#pragma unroll
        for (int g = 0; g < 4; ++g) {
            int idx = t * 4 + g;
            if (idx < n) m = max(m, deg[perm[idx]]);
        }
        qlen[t] = m;
    }
}

// ---------------- exclusive scan (3-phase) ----------------
__global__ void k_scan1(const int* __restrict__ in, int* __restrict__ outp,
                        int* __restrict__ bsum, int n) {
    __shared__ int sm[256];
    int tid = threadIdx.x;
    int i = blockIdx.x * 256 + tid;
    int v = (i < n) ? in[i] : 0;
    sm[tid] = v;
    __syncthreads();
#pragma unroll
    for (int o = 1; o < 256; o <<= 1) {
        int t = (tid >= o) ? sm[tid - o] : 0;
        __syncthreads();
        sm[tid] += t;
        __syncthreads();
    }
    if (i <= n) outp[i] = sm[tid] - v;  // exclusive
    if (tid == 255) bsum[blockIdx.x] = sm[255];
}

__global__ void k_scan2(int* __restrict__ bsum, int nb) {
    __shared__ int sm[512];
    int tid = threadIdx.x;
    int v = (tid < nb) ? bsum[tid] : 0;
    sm[tid] = v;
    __syncthreads();
    for (int o = 1; o < 512; o <<= 1) {
        int t = (tid >= o) ? sm[tid - o] : 0;
        __syncthreads();
        sm[tid] += t;
        __syncthreads();
    }
    if (tid < nb) bsum[tid] = sm[tid] - v;
}

__global__ void k_scan3(int* __restrict__ outp, const int* __restrict__ bsum, int n) {
    int i = blockIdx.x * 256 + threadIdx.x;
    if (i <= n) outp[i] += bsum[blockIdx.x];
}

// ---------------- quad-interleaved CSR scatter (sorted quads) --------------
// node d sits at sorted position pos[d]; its quad q = pos[d]>>2, lane g = pos[d]&3.
// entry position = (qptr[q] + slot)*4 + g. Entries store ORIGINAL src id.
__global__ void k_csr(const int* __restrict__ src, const int* __restrict__ dst,
                      const float* __restrict__ dinv, const int* __restrict__ qptr,
                      const int* __restrict__ pos, int* __restrict__ fill,
                      uint2* __restrict__ qpk, int E) {
    int e = blockIdx.x * blockDim.x + threadIdx.x;
    if (e < E) {
        int s = src[e], d = dst[e];
        int slot = atomicAdd(&fill[d], 1);
        int pd = pos[d];
        int p = (qptr[pd >> 2] + slot) * 4 + (pd & 3);
        uint2 v;
        v.x = (unsigned)s;
        v.y = (unsigned)__float_as_int(dinv[s] * dinv[d]);
        __builtin_nontemporal_store(*(unsigned long long*)&v,
                                    (unsigned long long*)&qpk[p]);
    }
}

// ---------------- error -> padded half rows + block partials ----------------
__global__ __launch_bounds__(256) void k_error(
    const float4* __restrict__ ys4, const int* __restrict__ y_true,
    const void* __restrict__ maskp, const unsigned int* __restrict__ flags,
    uint2* __restrict__ err, float* __restrict__ psig, float* __restrict__ pcnt,
    int total16) {
    unsigned int fl = *flags;
    float a = 0.f, cnt = 0.f;
    for (int i = blockIdx.x * blockDim.x + threadIdx.x; i < total16;
         i += gridDim.x * blockDim.x) {
        int node = i >> 4, cl = i & 15;
        uint2 w = make_uint2(0u, 0u);
        if (cl < NQ && read_mask(maskp, fl, node)) {
            int yt = y_true[node];
            float4 ys = ys4[node * NQ + cl];
            int c0 = cl * 4;
            float e0 = ((c0 + 0) == yt ? 1.f : 0.f) - ys.x;
            float e1 = ((c0 + 1) == yt ? 1.f : 0.f) - ys.y;
            float e2 = ((c0 + 2) == yt ? 1.f : 0.f) - ys.z;
            float e3 = ((c0 + 3) == yt ? 1.f : 0.f) - ys.w;
            a += fabsf(e0) + fabsf(e1) + fabsf(e2) + fabsf(e3);
            if (cl == 0) cnt += 1.f;
            __half2 h01 = __floats2half2_rn(e0, e1);
            __half2 h23 = __floats2half2_rn(e2, e3);
            w.x = *(unsigned*)&h01;
            w.y = *(unsigned*)&h23;
        }
        err[((size_t)node << 4) + cl] = w;
    }
    __shared__ float sA[256];
    __shared__ float sB[256];
    int tid = threadIdx.x;
    sA[tid] = a; sB[tid] = cnt;
    __syncthreads();
    for (int o = 128; o; o >>= 1) {
        if (tid < o) { sA[tid] += sA[tid + o]; sB[tid] += sB[tid + o]; }
        __syncthreads();
    }
    if (tid == 0) { psig[blockIdx.x] = sA[0]; pcnt[blockIdx.x] = sB[0]; }
}

__global__ __launch_bounds__(256) void k_reduce(
    const float* __restrict__ psig, const float* __restrict__ pcnt,
    float* __restrict__ s_sig, float* __restrict__ s_cnt, int nb) {
    float a = 0.f, c = 0.f;
    for (int i = threadIdx.x; i < nb; i += 256) { a += psig[i]; c += pcnt[i]; }
    __shared__ float sA[256];
    __shared__ float sB[256];
    int tid = threadIdx.x;
    sA[tid] = a; sB[tid] = c;
    __syncthreads();
    for (int o = 128; o; o >>= 1) {
        if (tid < o) { sA[tid] += sA[tid + o]; sB[tid] += sB[tid + o]; }
        __syncthreads();
    }
    if (tid == 0) { *s_sig = sA[0]; *s_cnt = sB[0]; }
}

// ---------------- propagation: 4 sorted nodes/wave, 16 lanes/node -----------
#define STEP(UU)                                                              \
    {                                                                         \
        uint2 xv;                                                             \
        {                                                                     \
            unsigned voff = ((UU).x << 7) + cl8;                              \
            xv = *(const uint2*)(xc + voff);                                  \
        }                                                                     \
        float nrm = __int_as_float((int)(UU).y);                              \
        __half2 h01 = *(__half2*)&xv.x;                                       \
        __half2 h23 = *(__half2*)&xv.y;                                       \
        acc0 = fmaf(nrm, __half2float(__low2half(h01)), acc0);                \
        acc1 = fmaf(nrm, __half2float(__high2half(h01)), acc1);               \
        acc2 = fmaf(nrm, __half2float(__low2half(h23)), acc2);                \
        acc3 = fmaf(nrm, __half2float(__high2half(h23)), acc3);               \
    }

template <int POST, int F32OUT>
__global__ __launch_bounds__(256) void k_prop(
    const int* __restrict__ qptr, const uint2* __restrict__ qpk,
    const int* __restrict__ perm, const void* __restrict__ xv_,
    const uint2* __restrict__ y0, void* __restrict__ outv,
    float alpha, float beta, int T, int n) {
    int wid = (blockIdx.x * blockDim.x + threadIdx.x) >> 6;
    if (wid >= T) return;
    int lane = threadIdx.x & 63;
    int g = lane >> 4, cl = lane & 15;
    int idx = wid * 4 + g;
    bool nvalid = (idx < n);
    int node = nvalid ? perm[idx] : 0;
    unsigned cl8 = (unsigned)cl << 3;
    const char* xc = (const char*)xv_;
    int sbeg = __builtin_amdgcn_readfirstlane(qptr[wid]);
    int send = __builtin_amdgcn_readfirstlane(qptr[wid + 1]);
    int steps = send - sbeg;
    const char* pkc = (const char*)(qpk + (size_t)sbeg * 4) + (size_t)g * 8;

    uint2 yv = y0[((size_t)node << 4) + cl];
    __half2 y01 = *(__half2*)&yv.x;
    __half2 y23 = *(__half2*)&yv.y;

    float acc0 = 0.f, acc1 = 0.f, acc2 = 0.f, acc3 = 0.f;
    int s = 0;
    for (; s + 4 <= steps; s += 4) {
        uint2 u0 = *(const uint2*)(pkc);
        uint2 u1 = *(const uint2*)(pkc + 32);
        uint2 u2 = *(const uint2*)(pkc + 64);
        uint2 u3 = *(const uint2*)(pkc + 96);
        STEP(u0) STEP(u1) STEP(u2) STEP(u3)
        pkc += 128;
    }
    for (; s < steps; ++s) {
        uint2 u0 = *(const uint2*)(pkc);
        STEP(u0)
        pkc += 32;
    }

    float v0 = fmaf(alpha, acc0, beta * __half2float(__low2half(y01)));
    float v1 = fmaf(alpha, acc1, beta * __half2float(__high2half(y01)));
    float v2 = fmaf(alpha, acc2, beta * __half2float(__low2half(y23)));
    float v3 = fmaf(alpha, acc3, beta * __half2float(__high2half(y23)));

    float r0, r1, r2, r3;
    if (POST == 0) {
        r0 = fminf(1.0f, fmaxf(-1.0f, v0));
        r1 = fminf(1.0f, fmaxf(-1.0f, v1));
        r2 = fminf(1.0f, fmaxf(-1.0f, v2));
        r3 = fminf(1.0f, fmaxf(-1.0f, v3));
    } else {
        bool val = (cl < NQ);
        float mx = val ? fmaxf(fmaxf(v0, v1), fmaxf(v2, v3)) : -3.0e38f;
#pragma unroll
        for (int o = 8; o; o >>= 1) mx = fmaxf(mx, __shfl_xor(mx, o));
        float e0 = val ? __expf(v0 - mx) : 0.f;
        float e1 = val ? __expf(v1 - mx) : 0.f;
        float e2 = val ? __expf(v2 - mx) : 0.f;
        float e3 = val ? __expf(v3 - mx) : 0.f;
        float ss = (e0 + e1) + (e2 + e3);
#pragma unroll
        for (int o = 8; o; o >>= 1) ss += __shfl_xor(ss, o);
        float inv = 1.0f / ss;
        r0 = e0 * inv; r1 = e1 * inv; r2 = e2 * inv; r3 = e3 * inv;
    }

    if (F32OUT) {
        if (nvalid && cl < NQ)
            ((float4*)outv)[(size_t)node * NQ + cl] = make_float4(r0, r1, r2, r3);
    } else {
        uint2 w = make_uint2(0u, 0u);
        if (cl < NQ) {
            __half2 h01 = __floats2half2_rn(r0, r1);
            __half2 h23 = __floats2half2_rn(r2, r3);
            w.x = *(unsigned*)&h01;
            w.y = *(unsigned*)&h23;
        }
        if (nvalid) ((uint2*)outv)[((size_t)node << 4) + cl] = w;
    }
}

// ---------------- scale + y0 build (padded half in/out) ----------------
__global__ __launch_bounds__(256) void k_scale(
    const uint2* __restrict__ sm_err, const float4* __restrict__ ys4,
    const int* __restrict__ y_true, const void* __restrict__ maskp,
    const unsigned int* __restrict__ flags, const float* __restrict__ s_sig,
    const float* __restrict__ s_cnt, uint2* __restrict__ y0, int n) {
    int i = blockIdx.x * blockDim.x + threadIdx.x;
    int node = i >> 4, cl = i & 15;
    if (node >= n) return;
    uint2 ev = sm_err[((size_t)node << 4) + cl];
    __half2 e01 = *(__half2*)&ev.x;
    __half2 e23 = *(__half2*)&ev.y;
    float v0 = __half2float(__low2half(e01));
    float v1 = __half2float(__high2half(e01));
    float v2 = __half2float(__low2half(e23));
    float v3 = __half2float(__high2half(e23));
    bool val = (cl < NQ);
    float a = val ? (fabsf(v0) + fabsf(v1)) + (fabsf(v2) + fabsf(v3)) : 0.f;
#pragma unroll
    for (int o = 8; o; o >>= 1) a += __shfl_xor(a, o);
    float sigma = (*s_sig) / (*s_cnt);
    float scale = sigma / a;
    if (isinf(scale) || scale > 1000.0f) scale = 1.0f;
    uint2 w = make_uint2(0u, 0u);
    if (val) {
        bool m = read_mask(maskp, *flags, node);
        int yt = y_true[node];
        float4 ys = ys4[node * NQ + cl];
        int c0 = cl * 4;
        float r0 = m ? ((c0 + 0) == yt ? 1.f : 0.f) : fmaf(scale, v0, ys.x);
        float r1 = m ? ((c0 + 1) == yt ? 1.f : 0.f) : fmaf(scale, v1, ys.y);
        float r2 = m ? ((c0 + 2) == yt ? 1.f : 0.f) : fmaf(scale, v2, ys.z);
        float r3 = m ? ((c0 + 3) == yt ? 1.f : 0.f) : fmaf(scale, v3, ys.w);
        __half2 h01 = __floats2half2_rn(r0, r1);
        __half2 h23 = __floats2half2_rn(r2, r3);
        w.x = *(unsigned*)&h01;
        w.y = *(unsigned*)&h23;
    }
    y0[((size_t)node << 4) + cl] = w;
}

extern "C" void kernel_launch(void* const* d_in, const int* in_sizes, int n_in,
                              void* d_out, int out_size, void* d_ws, size_t ws_size,
                              hipStream_t stream) {
    const int* y_true = (const int*)d_in[0];
    const float* y_soft = (const float*)d_in[1];
    const void* maskp = d_in[2];
    const int* ei = (const int*)d_in[3];
    const int n = in_sizes[0];
    const int E = in_sizes[3] / 2;
    const int* src = ei;
    const int* dst = ei + E;
    const int T = (n + 3) / 4;              // quads

    char* ws = (char*)d_ws;
    size_t off = 0;
    auto alloc = [&](size_t bytes) -> char* {
        char* p = ws + off;
        off += (bytes + 63) & ~(size_t)63;
        return p;
    };
    int* deg = (int*)alloc((size_t)n * 4);
    int* fill = (int*)alloc((size_t)n * 4);
    int* hist = (int*)alloc(NBIN * 4);
    int* binfill = (int*)alloc(NBIN * 4);
    unsigned int* flags = (unsigned int*)alloc(4);
    size_t zero_bytes = off;                 // zeroed every call
    int* binptr = (int*)alloc(NBIN * 4);
    int* perm = (int*)alloc((size_t)n * 4);
    int* pos = (int*)alloc((size_t)n * 4);
    float* s_sig = (float*)alloc(4);
    float* s_cnt = (float*)alloc(4);
    float* psig = (float*)alloc(2048 * 4);
    float* pcnt = (float*)alloc(2048 * 4);
    float* dinv = (float*)alloc((size_t)n * 4);
    int* qlen = (int*)alloc((size_t)T * 4);
    int* qptr = (int*)alloc((size_t)(T + 1) * 4);
    int* bsum = (int*)alloc(4096);
    const size_t QPK_CAP = (size_t)E + (size_t)E / 4 + 4096;  // entries
    uint2* qpk = (uint2*)alloc(QPK_CAP * 8);
    size_t fbytes = ((size_t)n * 16 + 64) * 8;   // padded rows (16 uint2/node)
    uint2* hE = (uint2*)alloc(fbytes);
    uint2* hA = (uint2*)alloc(fbytes);
    uint2* hB = (uint2*)alloc(fbytes);
    (void)ws_size;

    hipMemsetAsync(d_ws, 0, zero_bytes, stream);
    hipMemsetAsync(qpk, 0, QPK_CAP * 8, stream);   // null edges = {src 0, norm 0}

    k_detect<<<98, 256, 0, stream>>>((const unsigned int*)maskp, n / 4, flags);
    k_deg<<<(E + 255) / 256, 256, 0, stream>>>(dst, deg, E);
    k_dinv<<<(n + 255) / 256, 256, 0, stream>>>(deg, dinv, n);

    // degree-sorted node order
    k_hist<<<(n + 255) / 256, 256, 0, stream>>>(deg, hist, n);
    k_binscan<<<1, NBIN, 0, stream>>>(hist, binptr);
    k_sort<<<(n + 255) / 256, 256, 0, stream>>>(deg, binptr, binfill, perm, pos, n);
    k_qlen<<<(T + 255) / 256, 256, 0, stream>>>(deg, perm, qlen, T, n);

    int nb1 = (T + 1 + 255) / 256;
    k_scan1<<<nb1, 256, 0, stream>>>(qlen, qptr, bsum, T);
    k_scan2<<<1, 512, 0, stream>>>(bsum, nb1);
    k_scan3<<<nb1, 256, 0, stream>>>(qptr, bsum, T);
    k_csr<<<(E + 255) / 256, 256, 0, stream>>>(src, dst, dinv, qptr, pos, fill, qpk, E);

    k_error<<<2048, 256, 0, stream>>>((const float4*)y_soft, y_true, maskp, flags,
                                      hE, psig, pcnt, n * 16);
    k_reduce<<<1, 256, 0, stream>>>(psig, pcnt, s_sig, s_cnt, 2048);

    const int pb = (T + 3) / 4;   // 4 waves (quads) per 256-thread block
    const int sb = (n * 16 + 255) / 256;
    const float A1 = 0.979f, B1 = (float)(1.0 - 0.979);
    const float A2 = 0.756f, B2 = (float)(1.0 - 0.756);

    // correct phase: 10 layers, post=clip. y0 = hE; ping-pong hA/hB.
    uint2* bufs[2] = { hA, hB };
    const uint2* x = hE;
    for (int it = 0; it < 10; ++it) {
        k_prop<0, 0><<<pb, 256, 0, stream>>>(qptr, qpk, perm, x, hE, bufs[it & 1],
                                             A1, B1, T, n);
        x = bufs[it & 1];
    }
    // x == hB holds smoothed_error; build y0 into hA
    k_scale<<<sb, 256, 0, stream>>>(x, (const float4*)y_soft, y_true, maskp, flags,
                                    s_sig, s_cnt, hA, n);

    // smooth phase: 10 layers, post=softmax. y0 = hA; ping-pong hE/hB.
    uint2* bufs2[2] = { hE, hB };
    x = hA;
    for (int it = 0; it < 9; ++it) {
        k_prop<1, 0><<<pb, 256, 0, stream>>>(qptr, qpk, perm, x, hA, bufs2[it & 1],
                                             A2, B2, T, n);
        x = bufs2[it & 1];
    }
    k_prop<1, 1><<<pb, 256, 0, stream>>>(qptr, qpk, perm, x, hA, d_out, A2, B2, T, n);
}

// Round 8
// 1601.878 us; speedup vs baseline: 1.5687x; 1.5687x over previous
//
#include <hip/hip_runtime.h>
#include <hip/hip_fp16.h>
#include <math.h>

#define C 40

// ---------------- mask dtype detection ----------------
__global__ void k_detect(const unsigned int* __restrict__ w, int nwords,
                         unsigned int* __restrict__ flags) {
    int i = blockIdx.x * blockDim.x + threadIdx.x;
    unsigned int viol = 0;
    for (; i < nwords; i += gridDim.x * blockDim.x) {
        unsigned int v = w[i];
        if (!(v == 0u || v == 1u)) viol |= 1u;
        if (!(v == 0u || v == 0x3F800000u)) viol |= 2u;
    }
    if (viol) atomicOr(flags, viol);
}

__device__ __forceinline__ bool read_mask(const void* mp, unsigned int fl, int n) {
    if ((fl & 1u) == 0u) return ((const int*)mp)[n] != 0;        // int32 {0,1}
    if ((fl & 2u) == 0u) return ((const float*)mp)[n] != 0.0f;   // float {0,1}
    return ((const unsigned char*)mp)[n] != 0;                   // bool bytes
}

// ---------------- degree / norm ----------------
__global__ void k_deg(const int* __restrict__ dst, int* __restrict__ deg, int E) {
    int i = blockIdx.x * blockDim.x + threadIdx.x;
    if (i < E) atomicAdd(&deg[dst[i]], 1);
}

__global__ void k_dinv(const int* __restrict__ deg, float* __restrict__ dinv, int n) {
    int i = blockIdx.x * blockDim.x + threadIdx.x;
    if (i < n) {
        int d = deg[i];
        dinv[i] = (d > 0) ? rsqrtf((float)d) : 0.0f;
    }
}

// ---------------- exclusive scan (3-phase) over deg -> rowptr ----------------
__global__ void k_scan1(const int* __restrict__ in, int* __restrict__ outp,
                        int* __restrict__ bsum, int n) {
    __shared__ int sm[256];
    int tid = threadIdx.x;
    int i = blockIdx.x * 256 + tid;
    int v = (i < n) ? in[i] : 0;
    sm[tid] = v;
    __syncthreads();
#pragma unroll
    for (int o = 1; o < 256; o <<= 1) {
        int t = (tid >= o) ? sm[tid - o] : 0;
        __syncthreads();
        sm[tid] += t;
        __syncthreads();
    }
    if (i <= n) outp[i] = sm[tid] - v;  // exclusive
    if (tid == 255) bsum[blockIdx.x] = sm[255];
}

__global__ void k_scan2(int* __restrict__ bsum, int nb) {
    __shared__ int sm[512];
    int tid = threadIdx.x;
    int v = (tid < nb) ? bsum[tid] : 0;
    sm[tid] = v;
    __syncthreads();
    for (int o = 1; o < 512; o <<= 1) {
        int t = (tid >= o) ? sm[tid - o] : 0;
        __syncthreads();
        sm[tid] += t;
        __syncthreads();
    }
    if (tid < nb) bsum[tid] = sm[tid] - v;
}

__global__ void k_scan3(int* __restrict__ outp, const int* __restrict__ bsum, int n) {
    int i = blockIdx.x * 256 + threadIdx.x;
    if (i <= n) outp[i] += bsum[blockIdx.x];
}

// ---------------- CSR scatter: pk[pos] = {src, norm} (normal store) --------
__global__ void k_csr(const int* __restrict__ src, const int* __restrict__ dst,
                      const float* __restrict__ dinv, const int* __restrict__ rowptr,
                      int* __restrict__ fill, unsigned long long* __restrict__ pk,
                      int E) {
    int e = blockIdx.x * blockDim.x + threadIdx.x;
    if (e < E) {
        int s = src[e], d = dst[e];
        int pos = rowptr[d] + atomicAdd(&fill[d], 1);
        unsigned long long u = (unsigned)s |
            ((unsigned long long)(unsigned)__float_as_int(dinv[s] * dinv[d]) << 32);
        pk[pos] = u;
    }
}

// ---------------- error -> split half layout + block partials ----------------
// split layout in byte buffer: A-part node*64 + c*2 (c<32); B-part n*64 + node*16 + (c-32)*2
__global__ __launch_bounds__(256) void k_error(
    const float4* __restrict__ ys4, const int* __restrict__ y_true,
    const void* __restrict__ maskp, const unsigned int* __restrict__ flags,
    char* __restrict__ err, float* __restrict__ psig, float* __restrict__ pcnt,
    int n) {
    unsigned int fl = *flags;
    unsigned boff = (unsigned)n * 64u;
    float a = 0.f, cnt = 0.f;
    int nq = n * 10;
    for (int i = blockIdx.x * blockDim.x + threadIdx.x; i < nq;
         i += gridDim.x * blockDim.x) {
        int node = i / 10;
        int q = i - node * 10;
        float e0 = 0.f, e1 = 0.f, e2 = 0.f, e3 = 0.f;
        if (read_mask(maskp, fl, node)) {
            int yt = y_true[node];
            float4 ys = ys4[i];
            int c0 = q * 4;
            e0 = ((c0 + 0) == yt ? 1.f : 0.f) - ys.x;
            e1 = ((c0 + 1) == yt ? 1.f : 0.f) - ys.y;
            e2 = ((c0 + 2) == yt ? 1.f : 0.f) - ys.z;
            e3 = ((c0 + 3) == yt ? 1.f : 0.f) - ys.w;
            a += fabsf(e0) + fabsf(e1) + fabsf(e2) + fabsf(e3);
            if (q == 0) cnt += 1.f;
        }
        __half2 h01 = __floats2half2_rn(e0, e1);
        __half2 h23 = __floats2half2_rn(e2, e3);
        uint2 w;
        w.x = *(unsigned*)&h01;
        w.y = *(unsigned*)&h23;
        unsigned off = (q < 8) ? (unsigned)node * 64u + (unsigned)q * 8u
                               : boff + (unsigned)node * 16u + (unsigned)(q - 8) * 8u;
        *(uint2*)(err + off) = w;
    }
    __shared__ float sA[256];
    __shared__ float sB[256];
    int tid = threadIdx.x;
    sA[tid] = a; sB[tid] = cnt;
    __syncthreads();
    for (int o = 128; o; o >>= 1) {
        if (tid < o) { sA[tid] += sA[tid + o]; sB[tid] += sB[tid + o]; }
        __syncthreads();
    }
    if (tid == 0) { psig[blockIdx.x] = sA[0]; pcnt[blockIdx.x] = sB[0]; }
}

__global__ __launch_bounds__(256) void k_reduce(
    const float* __restrict__ psig, const float* __restrict__ pcnt,
    float* __restrict__ s_sig, float* __restrict__ s_cnt, int nb) {
    float a = 0.f, c = 0.f;
    for (int i = threadIdx.x; i < nb; i += 256) { a += psig[i]; c += pcnt[i]; }
    __shared__ float sA[256];
    __shared__ float sB[256];
    int tid = threadIdx.x;
    sA[tid] = a; sB[tid] = c;
    __syncthreads();
    for (int o = 128; o; o >>= 1) {
        if (tid < o) { sA[tid] += sA[tid + o]; sB[tid] += sB[tid + o]; }
        __syncthreads();
    }
    if (tid == 0) { *s_sig = sA[0]; *s_cnt = sB[0]; }
}

// ---------------- propagation: 1 node/wave, split-layout fp16 gather --------
// lanes 0-31 cover classes 0-31 (64B aligned A row = 1 line);
// lanes 32-39 cover classes 32-39 (16B packed B row, 1.6MB L2-resident).
// One global_load_ushort per edge per wave; pk via scalar loads.
#define PKLOAD(U, EE)                                                        \
    _Pragma("unroll") for (int j = 0; j < GRP; ++j) { U[j] = pk8[(EE) + j]; }

#define GATH(XV, U)                                                          \
    _Pragma("unroll") for (int j = 0; j < GRP; ++j) {                        \
        unsigned s = (unsigned)(U[j] & 0xffffffffu);                         \
        XV[j] = *(const __half*)(xc + ((s << shift) + aoff));                \
    }

#define FMAG(U, XV)                                                          \
    _Pragma("unroll") for (int j = 0; j < GRP; ++j) {                        \
        acc[j & 3] = fmaf(__int_as_float((int)(U[j] >> 32)),                 \
                          __half2float(XV[j]), acc[j & 3]);                  \
    }

template <int POST, int F32OUT>
__global__ __launch_bounds__(256) void k_prop(
    const int* __restrict__ rowptr, const unsigned long long* __restrict__ pk8,
    const char* __restrict__ xc, const char* __restrict__ y0,
    void* __restrict__ outv, float alpha, float beta, int n) {
    int wid = (blockIdx.x * blockDim.x + threadIdx.x) >> 6;
    int lane = threadIdx.x & 63;
    if (wid >= n) return;
    int beg = __builtin_amdgcn_readfirstlane(rowptr[wid]);
    int end = __builtin_amdgcn_readfirstlane(rowptr[wid + 1]);
    bool isA = (lane < 32);
    unsigned shift = isA ? 6u : 4u;
    unsigned aoff = isA ? (unsigned)(lane * 2)
                        : (unsigned)n * 64u + (unsigned)((lane - 32) * 2);

    float y0v = __half2float(*(const __half*)(y0 + (((unsigned)wid << shift) + aoff)));
    float acc[4] = {0.f, 0.f, 0.f, 0.f};
    int e = beg;
    {
        enum { GRP = 16 };
        for (; e + GRP <= end; e += GRP) {
            unsigned long long u[GRP];
            __half xv[GRP];
            PKLOAD(u, e)
            GATH(xv, u)
            FMAG(u, xv)
        }
    }
    {
        enum { GRP = 8 };
        if (e + GRP <= end) {
            unsigned long long u[GRP];
            __half xv[GRP];
            PKLOAD(u, e)
            GATH(xv, u)
            FMAG(u, xv)
            e += GRP;
        }
    }
    for (; e < end; ++e) {
        unsigned long long u = pk8[e];
        unsigned s = (unsigned)(u & 0xffffffffu);
        float xv = __half2float(*(const __half*)(xc + ((s << shift) + aoff)));
        acc[0] = fmaf(__int_as_float((int)(u >> 32)), xv, acc[0]);
    }
    float a = (acc[0] + acc[1]) + (acc[2] + acc[3]);
    float v = fmaf(alpha, a, beta * y0v);

    float res;
    if (POST == 0) {
        res = fminf(1.0f, fmaxf(-1.0f, v));
    } else {
        float mx = (lane < C) ? v : -3.0e38f;
#pragma unroll
        for (int o = 32; o; o >>= 1) mx = fmaxf(mx, __shfl_xor(mx, o));
        float ex = (lane < C) ? __expf(v - mx) : 0.0f;
        float s = ex;
#pragma unroll
        for (int o = 32; o; o >>= 1) s += __shfl_xor(s, o);
        res = ex / s;
    }
    if (lane < C) {
        if (F32OUT) {
            ((float*)outv)[(size_t)wid * C + lane] = res;
        } else {
            *(__half*)((char*)outv + (((unsigned)wid << shift) + aoff)) =
                __float2half(res);
        }
    }
}

// ---------------- scale + y0 build (split half in/out): one wave per node ---
__global__ __launch_bounds__(256) void k_scale(
    const char* __restrict__ sm_err, const float* __restrict__ y_soft,
    const int* __restrict__ y_true, const void* __restrict__ maskp,
    const unsigned int* __restrict__ flags, const float* __restrict__ s_sig,
    const float* __restrict__ s_cnt, char* __restrict__ y0, int n) {
    int wid = (blockIdx.x * blockDim.x + threadIdx.x) >> 6;
    int lane = threadIdx.x & 63;
    if (wid >= n) return;
    bool isA = (lane < 32);
    unsigned shift = isA ? 6u : 4u;
    unsigned aoff = isA ? (unsigned)(lane * 2)
                        : (unsigned)n * 64u + (unsigned)((lane - 32) * 2);
    float v = 0.f, a = 0.f;
    if (lane < C) {
        v = __half2float(*(const __half*)(sm_err + (((unsigned)wid << shift) + aoff)));
        a = fabsf(v);
    }
#pragma unroll
    for (int o = 32; o; o >>= 1) a += __shfl_xor(a, o);
    float sigma = (*s_sig) / (*s_cnt);
    float scale = sigma / a;
    if (isinf(scale) || scale > 1000.0f) scale = 1.0f;
    if (lane < C) {
        bool m = read_mask(maskp, *flags, wid);
        float yc = fmaf(scale, v, y_soft[(size_t)wid * C + lane]);
        float r = m ? ((lane == y_true[wid]) ? 1.0f : 0.0f) : yc;
        *(__half*)(y0 + (((unsigned)wid << shift) + aoff)) = __float2half(r);
    }
}

extern "C" void kernel_launch(void* const* d_in, const int* in_sizes, int n_in,
                              void* d_out, int out_size, void* d_ws, size_t ws_size,
                              hipStream_t stream) {
    const int* y_true = (const int*)d_in[0];
    const float* y_soft = (const float*)d_in[1];
    const void* maskp = d_in[2];
    const int* ei = (const int*)d_in[3];
    const int n = in_sizes[0];
    const int E = in_sizes[3] / 2;
    const int* src = ei;
    const int* dst = ei + E;

    char* ws = (char*)d_ws;
    size_t off = 0;
    auto alloc = [&](size_t bytes) -> char* {
        char* p = ws + off;
        off += (bytes + 255) & ~(size_t)255;
        return p;
    };
    int* deg = (int*)alloc((size_t)n * 4);
    int* fill = (int*)alloc((size_t)n * 4);
    unsigned int* flags = (unsigned int*)alloc(4);
    size_t zero_bytes = off;                 // zeroed every call
    float* s_sig = (float*)alloc(4);
    float* s_cnt = (float*)alloc(4);
    float* psig = (float*)alloc(2048 * 4);
    float* pcnt = (float*)alloc(2048 * 4);
    float* dinv = (float*)alloc((size_t)n * 4);
    int* rowptr = (int*)alloc((size_t)(n + 1) * 4);
    int* bsum = (int*)alloc(4096);
    unsigned long long* pk = (unsigned long long*)alloc((size_t)E * 8);
    size_t fb = (size_t)n * 80 + 512;        // split feature buffer (64B A + 16B B)
    char* hE = alloc(fb);
    char* hY = alloc(fb);
    char* hA = alloc(fb);
    char* hB = alloc(fb);
    (void)ws_size;

    hipMemsetAsync(d_ws, 0, zero_bytes, stream);

    k_detect<<<98, 256, 0, stream>>>((const unsigned int*)maskp, n / 4, flags);
    k_deg<<<(E + 255) / 256, 256, 0, stream>>>(dst, deg, E);
    k_dinv<<<(n + 255) / 256, 256, 0, stream>>>(deg, dinv, n);

    int nb1 = (n + 1 + 255) / 256;
    k_scan1<<<nb1, 256, 0, stream>>>(deg, rowptr, bsum, n);
    k_scan2<<<1, 512, 0, stream>>>(bsum, nb1);
    k_scan3<<<nb1, 256, 0, stream>>>(rowptr, bsum, n);
    k_csr<<<(E + 255) / 256, 256, 0, stream>>>(src, dst, dinv, rowptr, fill, pk, E);

    k_error<<<2048, 256, 0, stream>>>((const float4*)y_soft, y_true, maskp, flags,
                                      hE, psig, pcnt, n);
    k_reduce<<<1, 256, 0, stream>>>(psig, pcnt, s_sig, s_cnt, 2048);

    const int pb = (n + 3) / 4;  // 4 waves per 256-thread block, 1 node per wave
    const float A1 = 0.979f, B1 = (float)(1.0 - 0.979);
    const float A2 = 0.756f, B2 = (float)(1.0 - 0.756);
    char* bufs[2] = { hA, hB };

    // correct phase: 10 layers, post = clip
    const char* x = hE;
    for (int it = 0; it < 10; ++it) {
        k_prop<0, 0><<<pb, 256, 0, stream>>>(rowptr, pk, x, hE, bufs[it & 1], A1, B1, n);
        x = bufs[it & 1];
    }
    // x == hB holds smoothed_error; build y0 into hY
    k_scale<<<pb, 256, 0, stream>>>(x, y_soft, y_true, maskp, flags, s_sig, s_cnt, hY, n);

    // smooth phase: 10 layers, post = softmax; final layer writes fp32 d_out
    x = hY;
    for (int it = 0; it < 9; ++it) {
        k_prop<1, 0><<<pb, 256, 0, stream>>>(rowptr, pk, x, hY, bufs[it & 1], A2, B2, n);
        x = bufs[it & 1];
    }
    k_prop<1, 1><<<pb, 256, 0, stream>>>(rowptr, pk, x, hY, d_out, A2, B2, n);
}